// Round 4
// baseline (82.741 us; speedup 1.0000x reference)
//
#include <hip/hip_runtime.h>
#include <hip/hip_cooperative_groups.h>

namespace cg = cooperative_groups;

#define INV_SQRT2 0.70710678118654752f
#define SQRT3     1.73205080756887729f
#define INV_SQRT3 0.57735026918962576f
#define INV_SQRT6 0.40824829046386302f
#define PW1_000   0.70710678118654752f   // sqrt(0.5)
#define PW1_112   2.23606797749978970f   // sqrt(5)
#define K_P       0.70710678118654752f   // PW1_011*INV_SQRT3 = PW1_101*INV_SQRT3 = PW1_111*INV_SQRT6
#define K_V0      0.40824829046386302f   // PW1_110*INV_SQRT3
#define PW2       0.15309310892394863f   // sqrt(3/128)
#define NC        0.31622776601683794f   // 1/sqrt(10)
#define NC2       0.18257418583505537f   // 1/sqrt(30)

#define RED16(v) { v += __shfl_xor(v,1,16); v += __shfl_xor(v,2,16); \
                   v += __shfl_xor(v,4,16); v += __shfl_xor(v,8,16); }

__global__ void __launch_bounds__(256) k_fused(
    const int* __restrict__ nf, const float* __restrict__ rv,
    const int* __restrict__ esrc, const int* __restrict__ edst,
    const float* __restrict__ emb,
    const float* __restrict__ t1_000, const float* __restrict__ t1_011,
    const float* __restrict__ t1_101, const float* __restrict__ t1_110,
    const float* __restrict__ t1_111, const float* __restrict__ t1_112,
    const float* __restrict__ t2_0e, const float* __restrict__ t2_1e,
    const float* __restrict__ t2_1o, const float* __restrict__ t2_2e,
    float* __restrict__ h, float* __restrict__ Mid, float* __restrict__ Dd,
    int* __restrict__ deg, float4* __restrict__ bucket,
    float* __restrict__ out, int n, int E, int CAP)
{
    cg::grid_group grid = cg::this_grid();
    const int tid = blockIdx.x * blockDim.x + threadIdx.x;
    const int nth = gridDim.x * blockDim.x;

    // ---- P0: weight dots (block 0, wave 0) -----------------------------
    if (blockIdx.x == 0 && threadIdx.x < 64) {
        int l = threadIdx.x;
        auto wdot = [&](const float* a, const float* b, int len) -> float {
            float v = (l < len) ? a[l] * b[l] : 0.0f;
            for (int off = 32; off > 0; off >>= 1) v += __shfl_down(v, off);
            return v;
        };
        float d0 = wdot(t1_000, t2_0e, 64);
        float d1 = wdot(t1_110, t2_0e, 64);
        float d2 = wdot(t1_011, t2_1e, 24);
        float d3 = wdot(t1_101, t2_1e, 24);
        float d4 = wdot(t1_111, t2_1o, 24);
        float d5 = wdot(t1_112, t2_2e, 16);
        if (l == 0) { Dd[0]=d0; Dd[1]=d1; Dd[2]=d2; Dd[3]=d3; Dd[4]=d4; Dd[5]=d5; }
    }
    // ---- P0: h channels 1..3 -------------------------------------------
    for (int i = tid; i < n * 3; i += nth) {
        int v = i / 3, cm = i - v * 3;          // channel cm+1
        int idx = nf[i];
        *(float4*)(h + v*16 + (cm + 1)*4) =
            make_float4(1.0f, SQRT3*emb[idx*3+0], SQRT3*emb[idx*3+1], SQRT3*emb[idx*3+2]);
    }
    // ---- P0: degree count + bucket fill (deg pre-zeroed by memset) -----
    for (int e = tid; e < E; e += nth) {
        int d = edst[e];
        if (d < n) {
            int s = esrc[e];
            float s1x = SQRT3 * (rv[s*3+0] - rv[d*3+0]);
            float s1y = SQRT3 * (rv[s*3+1] - rv[d*3+1]);
            float s1z = SQRT3 * (rv[s*3+2] - rv[d*3+2]);
            int pos = atomicAdd(deg + d, 1);
            if (pos < CAP)
                bucket[(size_t)d*CAP + pos] = make_float4(s1x, s1y, s1z, __int_as_float(s));
        }
    }
    grid.sync();

    // ---- P1: h0 gather (16 lanes/node) ---------------------------------
    for (int i = tid; i < n * 16; i += nth) {
        int d = i >> 4, ln = i & 15;
        int cnt = deg[d]; int cc = cnt < CAP ? cnt : CAP;
        const float4* B = bucket + (size_t)d*CAP;
        float ax = 0.f, ay = 0.f, az = 0.f;
        for (int p = ln; p < cc; p += 16) {
            float4 t = B[p];
            ax += t.x; ay += t.y; az += t.z;
        }
        RED16(ax) RED16(ay) RED16(az)
        if (ln == 0)
            *(float4*)(h + d*16) =
                make_float4(INV_SQRT2*(float)cnt, INV_SQRT2*ax, INV_SQRT2*ay, INV_SQRT2*az);
    }
    grid.sync();

    // ---- P2: channel-summed Mid[d][16] (16 lanes/node: c=ln>>2, sub=ln&3)
    for (int i = tid; i < n * 16; i += nth) {
        int d = i >> 4, ln = i & 15;
        int c = ln >> 2, sub = ln & 3;
        int cnt = deg[d]; int cc = cnt < CAP ? cnt : CAP;
        const float4* B = bucket + (size_t)d*CAP;
        float A0=0.f, A1=0.f;
        float px=0.f, py=0.f, pz=0.f;
        float qx=0.f, qy=0.f, qz=0.f;
        float cx=0.f, cy=0.f, cz=0.f;
        float t0=0.f, t1=0.f, t2=0.f, t3=0.f, t4=0.f;
        for (int p = sub; p < cc; p += 4) {
            float4 t = B[p];
            int s = __float_as_int(t.w);
            float s1x = t.x, s1y = t.y, s1z = t.z;
            float4 hv = *(const float4*)(h + s*16 + c*4);
            float a0 = hv.x, a1x = hv.y, a1y = hv.z, a1z = hv.w;
            A0 += a0;
            A1 += a1x*s1x + a1y*s1y + a1z*s1z;
            px += a0*s1x; py += a0*s1y; pz += a0*s1z;
            qx += a1x;    qy += a1y;    qz += a1z;
            cx += a1y*s1z - a1z*s1y;
            cy += a1z*s1x - a1x*s1z;
            cz += a1x*s1y - a1y*s1x;
            t0 += a1x*s1y + a1y*s1x;
            t1 += a1y*s1z + a1z*s1y;
            t2 += 2.0f*a1z*s1z - a1x*s1x - a1y*s1y;
            t3 += a1x*s1z + a1z*s1x;
            t4 += a1x*s1x - a1y*s1y;
        }
        RED16(A0) RED16(A1)
        RED16(px) RED16(py) RED16(pz)
        RED16(qx) RED16(qy) RED16(qz)
        RED16(cx) RED16(cy) RED16(cz)
        RED16(t0) RED16(t1) RED16(t2) RED16(t3) RED16(t4)
        if (ln == 0) {
            const float kA = INV_SQRT2 * PW1_000;
            const float kB = INV_SQRT2 * K_V0;
            const float kP = INV_SQRT2 * K_P;
            const float kT = INV_SQRT2 * PW1_112 * NC;
            const float kU = INV_SQRT2 * PW1_112 * NC2;
            float4* md = (float4*)(Mid + d*16);
            md[0] = make_float4(kA*A0, kB*A1, kP*px, kP*py);
            md[1] = make_float4(kP*pz, kP*qx, kP*qy, kP*qz);
            md[2] = make_float4(kP*cx, kP*cy, kP*cz, kT*t0);
            md[3] = make_float4(kT*t1, kU*t2, kT*t3, kT*t4);
        }
    }
    grid.sync();

    // ---- P3: output gather (16 lanes/node) -----------------------------
    for (int i = tid; i < n * 16; i += nth) {
        int d = i >> 4, ln = i & 15;
        int cnt = deg[d]; int cc = cnt < CAP ? cnt : CAP;
        const float4* B = bucket + (size_t)d*CAP;
        float D00 = Dd[0], D01 = Dd[1], D2a = Dd[2], D2b = Dd[3], D3 = Dd[4], D4 = Dd[5];
        float ox = 0.f, oy = 0.f, oz = 0.f;
        for (int p = ln; p < cc; p += 16) {
            float4 t = B[p];
            int s = __float_as_int(t.w);
            float s1x = t.x, s1y = t.y, s1z = t.z;
            const float4* m4 = (const float4*)(Mid + s*16);
            float4 ga = m4[0], gb = m4[1], gc = m4[2], gd = m4[3];
            float G0=ga.x, G1=ga.y, G2=ga.z, G3=ga.w;
            float G4=gb.x, G5=gb.y, G6=gb.z, G7=gb.w;
            float G8=gc.x, G9=gc.y, G10=gc.z, G11=gc.w;
            float G12=gd.x, G13=gd.y, G14=gd.z, G15=gd.w;
            // q1
            float q = INV_SQRT3 * (G0*D00 + G1*D01);
            ox += q * s1x; oy += q * s1y; oz += q * s1z;
            // q2
            float c1x = G3*s1z - G4*s1y;
            float c1y = G4*s1x - G2*s1z;
            float c1z = G2*s1y - G3*s1x;
            float c2x = G6*s1z - G7*s1y;
            float c2y = G7*s1x - G5*s1z;
            float c2z = G5*s1y - G6*s1x;
            ox += INV_SQRT6 * (D2a*c1x + D2b*c2x);
            oy += INV_SQRT6 * (D2a*c1y + D2b*c2y);
            oz += INV_SQRT6 * (D2a*c1z + D2b*c2z);
            // q3
            ox += INV_SQRT3 * D3 * G8;
            oy += INV_SQRT3 * D3 * G9;
            oz += INV_SQRT3 * D3 * G10;
            // q4
            ox += D4 * (NC*(s1y*G11 + s1z*G14 + s1x*G15) - NC2*s1x*G13);
            oy += D4 * (NC*(s1x*G11 + s1z*G12 - s1y*G15) - NC2*s1y*G13);
            oz += D4 * (NC*(s1y*G12 + s1x*G14) + 2.0f*NC2*s1z*G13);
        }
        RED16(ox) RED16(oy) RED16(oz)
        if (ln == 0) {
            out[d*3+0] = PW2 * INV_SQRT2 * ox;
            out[d*3+1] = PW2 * INV_SQRT2 * oy;
            out[d*3+2] = PW2 * INV_SQRT2 * oz;
        }
    }
}

extern "C" void kernel_launch(void* const* d_in, const int* in_sizes, int n_in,
                              void* d_out, int out_size, void* d_ws, size_t ws_size,
                              hipStream_t stream) {
    const int*   nf     = (const int*)  d_in[0];
    const float* rv     = (const float*)d_in[1];
    const int*   esrc   = (const int*)  d_in[2];
    const int*   edst   = (const int*)  d_in[3];
    const float* emb    = (const float*)d_in[4];
    const float* t1_000 = (const float*)d_in[5];
    const float* t1_011 = (const float*)d_in[6];
    const float* t1_101 = (const float*)d_in[7];
    const float* t1_110 = (const float*)d_in[8];
    const float* t1_111 = (const float*)d_in[9];
    const float* t1_112 = (const float*)d_in[10];
    const float* t2_0e  = (const float*)d_in[11];
    const float* t2_1e  = (const float*)d_in[12];
    const float* t2_1o  = (const float*)d_in[13];
    const float* t2_2e  = (const float*)d_in[14];

    int n = in_sizes[1] / 3;   // 2048 nodes
    int E = in_sizes[2];       // 40960 edges
    int CAP = 64;              // max in-degree capacity (mean deg = 20)

    float4* bucket = (float4*)d_ws;                       // n*CAP float4 (2 MiB)
    float*  h      = (float*)(bucket + (size_t)n * CAP);  // n*16 floats
    float*  Mid    = h + (size_t)n * 16;                  // n*16 floats
    float*  Dd     = Mid + (size_t)n * 16;                // 8 floats
    int*    deg    = (int*)(Dd + 8);                      // n ints
    float*  out    = (float*)d_out;

    hipMemsetAsync(deg, 0, (size_t)n * sizeof(int), stream);

    void* args[] = { &nf, &rv, &esrc, &edst, &emb,
                     &t1_000, &t1_011, &t1_101, &t1_110, &t1_111, &t1_112,
                     &t2_0e, &t2_1e, &t2_1o, &t2_2e,
                     &h, &Mid, &Dd, &deg, &bucket, &out, &n, &E, &CAP };
    hipLaunchCooperativeKernel(reinterpret_cast<void*>(k_fused),
                               dim3(128), dim3(256), args, 0, stream);
}

// Round 5
// 32.031 us; speedup vs baseline: 2.5832x; 2.5832x over previous
//
#include <hip/hip_runtime.h>

#define INV_SQRT2 0.70710678118654752f
#define SQRT3     1.73205080756887729f
#define INV_SQRT3 0.57735026918962576f
#define INV_SQRT6 0.40824829046386302f
#define PW1_000   0.70710678118654752f   // sqrt(0.5)
#define PW1_112   2.23606797749978970f   // sqrt(5)
#define K_P       0.70710678118654752f   // PW1_011*INV_SQRT3 = PW1_101*INV_SQRT3 = PW1_111*INV_SQRT6
#define K_V0      0.40824829046386302f   // PW1_110*INV_SQRT3
#define PW2       0.15309310892394863f   // sqrt(3/128)
#define NC        0.31622776601683794f   // 1/sqrt(10)
#define NC2       0.18257418583505537f   // 1/sqrt(30)

#define RED32(v) { v += __shfl_xor(v,1,32); v += __shfl_xor(v,2,32); \
                   v += __shfl_xor(v,4,32); v += __shfl_xor(v,8,32); \
                   v += __shfl_xor(v,16,32); }

// ---- prep: weight dots + H channels 1..3 + bucket/deg/h0 scatter -------
// H[v][0] = h0 (accumulated via atomics, pre-zeroed); H[v][1..3] = [1, sqrt3*emb[nf]]
__global__ void __launch_bounds__(256) k_prep(
    const int* __restrict__ nf, const float* __restrict__ rv,
    const int* __restrict__ esrc, const int* __restrict__ edst,
    const float* __restrict__ emb,
    const float* __restrict__ t1_000, const float* __restrict__ t1_011,
    const float* __restrict__ t1_101, const float* __restrict__ t1_110,
    const float* __restrict__ t1_111, const float* __restrict__ t1_112,
    const float* __restrict__ t2_0e, const float* __restrict__ t2_1e,
    const float* __restrict__ t2_1o, const float* __restrict__ t2_2e,
    float* __restrict__ Dd, float4* __restrict__ H,
    int* __restrict__ deg, float4* __restrict__ bucket,
    int n, int E, int CAP)
{
    if (blockIdx.x == 0 && threadIdx.x < 64) {
        int l = threadIdx.x;
        auto wdot = [&](const float* a, const float* b, int len) -> float {
            float v = (l < len) ? a[l] * b[l] : 0.0f;
            for (int off = 32; off > 0; off >>= 1) v += __shfl_down(v, off);
            return v;
        };
        float d0 = wdot(t1_000, t2_0e, 64);
        float d1 = wdot(t1_110, t2_0e, 64);
        float d2 = wdot(t1_011, t2_1e, 24);
        float d3 = wdot(t1_101, t2_1e, 24);
        float d4 = wdot(t1_111, t2_1o, 24);
        float d5 = wdot(t1_112, t2_2e, 16);
        if (l == 0) { Dd[0]=d0; Dd[1]=d1; Dd[2]=d2; Dd[3]=d3; Dd[4]=d4; Dd[5]=d5; }
    }
    const int tid = blockIdx.x * blockDim.x + threadIdx.x;
    const int nth = gridDim.x * blockDim.x;
    for (int i = tid; i < n * 3; i += nth) {
        int v = i / 3, cm = i - v * 3;          // channel cm+1
        int idx = nf[i];
        H[v*4 + cm + 1] =
            make_float4(1.0f, SQRT3*emb[idx*3+0], SQRT3*emb[idx*3+1], SQRT3*emb[idx*3+2]);
    }
    for (int e = tid; e < E; e += nth) {
        int d = edst[e];
        if (d >= n) continue;                   // padded edge
        int s = esrc[e];
        float s1x = SQRT3 * (rv[s*3+0] - rv[d*3+0]);
        float s1y = SQRT3 * (rv[s*3+1] - rv[d*3+1]);
        float s1z = SQRT3 * (rv[s*3+2] - rv[d*3+2]);
        int pos = atomicAdd(deg + d, 1);
        if (pos < CAP)
            bucket[(size_t)d*CAP + pos] = make_float4(s1x, s1y, s1z, __int_as_float(s));
        float* h0 = (float*)(H + d*4);
        atomicAdd(h0 + 0, INV_SQRT2);
        atomicAdd(h0 + 1, INV_SQRT2 * s1x);
        atomicAdd(h0 + 2, INV_SQRT2 * s1y);
        atomicAdd(h0 + 3, INV_SQRT2 * s1z);
    }
}

// ---- gather 2: channel-summed Mid[d][16]; 32 lanes/node ----------------
// lane = (c<<3)|sub : channel c in [0,4), edge-split sub in [0,8)
__global__ void __launch_bounds__(256) k_g2(
    const float4* __restrict__ bucket, const int* __restrict__ deg,
    const float4* __restrict__ H, float* __restrict__ Mid, int n, int CAP)
{
    int tid = blockIdx.x * blockDim.x + threadIdx.x;
    if (tid >= n * 32) return;
    int d = tid >> 5, ln = tid & 31;
    int c = ln >> 3, sub = ln & 7;
    int cnt = deg[d]; int cc = cnt < CAP ? cnt : CAP;
    const float4* B = bucket + (size_t)d * CAP;
    float A0=0.f, A1=0.f;
    float px=0.f, py=0.f, pz=0.f;
    float qx=0.f, qy=0.f, qz=0.f;
    float cx=0.f, cy=0.f, cz=0.f;
    float t0=0.f, t1=0.f, t2=0.f, t3=0.f, t4=0.f;
    for (int p = sub; p < cc; p += 8) {
        float4 t = B[p];
        int s = __float_as_int(t.w);
        float s1x = t.x, s1y = t.y, s1z = t.z;
        float4 hv = H[s*4 + c];
        float a0 = hv.x, a1x = hv.y, a1y = hv.z, a1z = hv.w;
        A0 += a0;
        A1 += a1x*s1x + a1y*s1y + a1z*s1z;
        px += a0*s1x; py += a0*s1y; pz += a0*s1z;
        qx += a1x;    qy += a1y;    qz += a1z;
        cx += a1y*s1z - a1z*s1y;
        cy += a1z*s1x - a1x*s1z;
        cz += a1x*s1y - a1y*s1x;
        t0 += a1x*s1y + a1y*s1x;
        t1 += a1y*s1z + a1z*s1y;
        t2 += 2.0f*a1z*s1z - a1x*s1x - a1y*s1y;
        t3 += a1x*s1z + a1z*s1x;
        t4 += a1x*s1x - a1y*s1y;
    }
    RED32(A0) RED32(A1)
    RED32(px) RED32(py) RED32(pz)
    RED32(qx) RED32(qy) RED32(qz)
    RED32(cx) RED32(cy) RED32(cz)
    RED32(t0) RED32(t1) RED32(t2) RED32(t3) RED32(t4)
    if (ln == 0) {
        const float kA = INV_SQRT2 * PW1_000;
        const float kB = INV_SQRT2 * K_V0;
        const float kP = INV_SQRT2 * K_P;
        const float kT = INV_SQRT2 * PW1_112 * NC;
        const float kU = INV_SQRT2 * PW1_112 * NC2;
        float4* md = (float4*)(Mid + d*16);
        md[0] = make_float4(kA*A0, kB*A1, kP*px, kP*py);
        md[1] = make_float4(kP*pz, kP*qx, kP*qy, kP*qz);
        md[2] = make_float4(kP*cx, kP*cy, kP*cz, kT*t0);
        md[3] = make_float4(kT*t1, kU*t2, kT*t3, kT*t4);
    }
}

// ---- gather 3: out[d]; 32 lanes/node -----------------------------------
__global__ void __launch_bounds__(256) k_g3(
    const float4* __restrict__ bucket, const int* __restrict__ deg,
    const float* __restrict__ Mid, const float* __restrict__ Dd,
    float* __restrict__ out, int n, int CAP)
{
    int tid = blockIdx.x * blockDim.x + threadIdx.x;
    if (tid >= n * 32) return;
    int d = tid >> 5, ln = tid & 31;
    int cnt = deg[d]; int cc = cnt < CAP ? cnt : CAP;
    const float4* B = bucket + (size_t)d * CAP;
    float D00 = Dd[0], D01 = Dd[1], D2a = Dd[2], D2b = Dd[3], D3 = Dd[4], D4 = Dd[5];
    float ox = 0.f, oy = 0.f, oz = 0.f;
    for (int p = ln; p < cc; p += 32) {
        float4 t = B[p];
        int s = __float_as_int(t.w);
        float s1x = t.x, s1y = t.y, s1z = t.z;
        const float4* m4 = (const float4*)(Mid + s*16);
        float4 ga = m4[0], gb = m4[1], gc = m4[2], gd = m4[3];
        float G0=ga.x, G1=ga.y, G2=ga.z, G3=ga.w;
        float G4=gb.x, G5=gb.y, G6=gb.z, G7=gb.w;
        float G8=gc.x, G9=gc.y, G10=gc.z, G11=gc.w;
        float G12=gd.x, G13=gd.y, G14=gd.z, G15=gd.w;
        // q1
        float q = INV_SQRT3 * (G0*D00 + G1*D01);
        ox += q * s1x; oy += q * s1y; oz += q * s1z;
        // q2
        float c1x = G3*s1z - G4*s1y;
        float c1y = G4*s1x - G2*s1z;
        float c1z = G2*s1y - G3*s1x;
        float c2x = G6*s1z - G7*s1y;
        float c2y = G7*s1x - G5*s1z;
        float c2z = G5*s1y - G6*s1x;
        ox += INV_SQRT6 * (D2a*c1x + D2b*c2x);
        oy += INV_SQRT6 * (D2a*c1y + D2b*c2y);
        oz += INV_SQRT6 * (D2a*c1z + D2b*c2z);
        // q3
        ox += INV_SQRT3 * D3 * G8;
        oy += INV_SQRT3 * D3 * G9;
        oz += INV_SQRT3 * D3 * G10;
        // q4
        ox += D4 * (NC*(s1y*G11 + s1z*G14 + s1x*G15) - NC2*s1x*G13);
        oy += D4 * (NC*(s1x*G11 + s1z*G12 - s1y*G15) - NC2*s1y*G13);
        oz += D4 * (NC*(s1y*G12 + s1x*G14) + 2.0f*NC2*s1z*G13);
    }
    RED32(ox) RED32(oy) RED32(oz)
    if (ln == 0) {
        out[d*3+0] = PW2 * INV_SQRT2 * ox;
        out[d*3+1] = PW2 * INV_SQRT2 * oy;
        out[d*3+2] = PW2 * INV_SQRT2 * oz;
    }
}

extern "C" void kernel_launch(void* const* d_in, const int* in_sizes, int n_in,
                              void* d_out, int out_size, void* d_ws, size_t ws_size,
                              hipStream_t stream) {
    const int*   nf     = (const int*)  d_in[0];
    const float* rv     = (const float*)d_in[1];
    const int*   esrc   = (const int*)  d_in[2];
    const int*   edst   = (const int*)  d_in[3];
    const float* emb    = (const float*)d_in[4];
    const float* t1_000 = (const float*)d_in[5];
    const float* t1_011 = (const float*)d_in[6];
    const float* t1_101 = (const float*)d_in[7];
    const float* t1_110 = (const float*)d_in[8];
    const float* t1_111 = (const float*)d_in[9];
    const float* t1_112 = (const float*)d_in[10];
    const float* t2_0e  = (const float*)d_in[11];
    const float* t2_1e  = (const float*)d_in[12];
    const float* t2_1o  = (const float*)d_in[13];
    const float* t2_2e  = (const float*)d_in[14];

    const int n = in_sizes[1] / 3;   // 2048 nodes
    const int E = in_sizes[2];       // 40960 edges
    const int CAP = 64;              // max in-degree capacity (mean deg = 20)

    // ws layout: [deg n ints][H n*4 float4][Mid n*16 floats][Dd 8][bucket n*CAP float4]
    int*    deg    = (int*)d_ws;
    float4* H      = (float4*)((char*)d_ws + (size_t)n * 4);
    float*  Mid    = (float*)(H + (size_t)n * 4);
    float*  Dd     = Mid + (size_t)n * 16;
    float4* bucket = (float4*)(Dd + 8);
    float*  out    = (float*)d_out;

    // zero deg + H (h0 accumulators; channels 1..3 overwritten in prep)
    hipMemsetAsync(d_ws, 0, (size_t)n * (4 + 64), stream);

    k_prep<<<(E + 255) / 256, 256, 0, stream>>>(
        nf, rv, esrc, edst, emb,
        t1_000, t1_011, t1_101, t1_110, t1_111, t1_112,
        t2_0e, t2_1e, t2_1o, t2_2e,
        Dd, H, deg, bucket, n, E, CAP);
    k_g2<<<(n * 32 + 255) / 256, 256, 0, stream>>>(bucket, deg, H, Mid, n, CAP);
    k_g3<<<(n * 32 + 255) / 256, 256, 0, stream>>>(bucket, deg, Mid, Dd, out, n, CAP);
}

// Round 6
// 21.741 us; speedup vs baseline: 3.8058x; 1.4733x over previous
//
#include <hip/hip_runtime.h>

#define INV_SQRT2 0.70710678118654752f
#define SQRT3     1.73205080756887729f
#define INV_SQRT3 0.57735026918962576f
#define INV_SQRT6 0.40824829046386302f
#define PW1_000   0.70710678118654752f   // sqrt(0.5)
#define PW1_112   2.23606797749978970f   // sqrt(5)
#define K_P       0.70710678118654752f   // PW1_011*INV_SQRT3 = PW1_101*INV_SQRT3 = PW1_111*INV_SQRT6
#define K_V0      0.40824829046386302f   // PW1_110*INV_SQRT3
#define PW2       0.15309310892394863f   // sqrt(3/128)
#define NC        0.31622776601683794f   // 1/sqrt(10)
#define NC2       0.18257418583505537f   // 1/sqrt(30)

#define RED8(v)  { v += __shfl_xor(v,1,8);  v += __shfl_xor(v,2,8);  v += __shfl_xor(v,4,8); }
#define RED16(v) { v += __shfl_xor(v,1,16); v += __shfl_xor(v,2,16); \
                   v += __shfl_xor(v,4,16); v += __shfl_xor(v,8,16); }

// lower_bound over monotone key: real edges keep src (globally sorted),
// pads (dst>=n) map to n and sit at the tail.
__device__ __forceinline__ int lbound(const int* __restrict__ esrc,
                                      const int* __restrict__ edst,
                                      int n, int E, int target) {
    int lo = 0, hi = E;
    while (lo < hi) {
        int mid = (lo + hi) >> 1;
        int d = edst[mid];
        int key = (d >= n) ? n : esrc[mid];
        if (key < target) lo = mid + 1; else hi = mid;
    }
    return lo;
}

// ---- prep: weight dots + per-edge s1 cache + per-node {offs, Hsum} -----
// Hsum[v] = sum over 4 channels of h[v][c] = h0[v] + [3, sqrt3 * sum emb]
// h0[v] = INV_SQRT2 * [cnt_v, sum_in s1]; in-edges of v = reversed out-run of v.
__global__ void __launch_bounds__(256) k_prep(
    const int* __restrict__ nf, const float* __restrict__ rv,
    const int* __restrict__ esrc, const int* __restrict__ edst,
    const float* __restrict__ emb,
    const float* __restrict__ t1_000, const float* __restrict__ t1_011,
    const float* __restrict__ t1_101, const float* __restrict__ t1_110,
    const float* __restrict__ t1_111, const float* __restrict__ t1_112,
    const float* __restrict__ t2_0e, const float* __restrict__ t2_1e,
    const float* __restrict__ t2_1o, const float* __restrict__ t2_2e,
    float* __restrict__ Dd, float4* __restrict__ Hsum,
    int* __restrict__ offs, float4* __restrict__ s1arr,
    int n, int E, int nodeBlocks)
{
    if ((int)blockIdx.x == nodeBlocks) {            // weight-dot block
        int l = threadIdx.x;
        if (l >= 64) return;
        auto wdot = [&](const float* a, const float* b, int len) -> float {
            float v = (l < len) ? a[l] * b[l] : 0.0f;
            for (int off = 32; off > 0; off >>= 1) v += __shfl_down(v, off);
            return v;
        };
        float d0 = wdot(t1_000, t2_0e, 64);
        float d1 = wdot(t1_110, t2_0e, 64);
        float d2 = wdot(t1_011, t2_1e, 24);
        float d3 = wdot(t1_101, t2_1e, 24);
        float d4 = wdot(t1_111, t2_1o, 24);
        float d5 = wdot(t1_112, t2_2e, 16);
        if (l == 0) { Dd[0]=d0; Dd[1]=d1; Dd[2]=d2; Dd[3]=d3; Dd[4]=d4; Dd[5]=d5; }
        return;
    }
    const int tid = blockIdx.x * 256 + threadIdx.x;
    const int nth = nodeBlocks * 256;

    // per-edge s1 cache: s1arr[e] = {sqrt3*(r[dst]-r[src]), bitcast(dst)}
    // (= the in-edge s1 vector of node src, with neighbor j=dst)
    for (int e = tid; e < E; e += nth) {
        int d = edst[e];
        if (d < n) {
            int s = esrc[e];
            s1arr[e] = make_float4(SQRT3*(rv[d*3+0]-rv[s*3+0]),
                                   SQRT3*(rv[d*3+1]-rv[s*3+1]),
                                   SQRT3*(rv[d*3+2]-rv[s*3+2]),
                                   __int_as_float(d));
        } else {
            s1arr[e] = make_float4(0.f, 0.f, 0.f, __int_as_float(0));  // pad, never read
        }
    }

    // per-node: 8 lanes
    if (tid < n * 8) {
        int v = tid >> 3, ln = tid & 7;
        int b = 0;
        if (ln == 0) b = lbound(esrc, edst, n, E, v);
        if (ln == 1) b = lbound(esrc, edst, n, E, v + 1);
        int lo = __shfl(b, 0, 8);
        int hi = __shfl(b, 1, 8);
        float sx = 0.f, sy = 0.f, sz = 0.f;
        for (int p = lo + ln; p < hi; p += 8) {
            int j = edst[p];
            sx += rv[j*3+0]; sy += rv[j*3+1]; sz += rv[j*3+2];
        }
        RED8(sx) RED8(sy) RED8(sz)
        if (ln == 0) {
            float cnt = (float)(hi - lo);
            float rx = rv[v*3+0], ry = rv[v*3+1], rz = rv[v*3+2];
            // h0 vector part: INV_SQRT2 * SQRT3 * (sum r[j] - cnt*r[v])
            float hx = INV_SQRT2 * SQRT3 * (sx - cnt*rx);
            float hy = INV_SQRT2 * SQRT3 * (sy - cnt*ry);
            float hz = INV_SQRT2 * SQRT3 * (sz - cnt*rz);
            int i0 = nf[v*3+0], i1 = nf[v*3+1], i2 = nf[v*3+2];
            float ex = emb[i0*3+0] + emb[i1*3+0] + emb[i2*3+0];
            float ey = emb[i0*3+1] + emb[i1*3+1] + emb[i2*3+1];
            float ez = emb[i0*3+2] + emb[i1*3+2] + emb[i2*3+2];
            Hsum[v] = make_float4(INV_SQRT2*cnt + 3.0f,
                                  hx + SQRT3*ex, hy + SQRT3*ey, hz + SQRT3*ez);
            offs[v] = lo;
            if (v == n - 1) offs[n] = hi;
        }
    }
}

// ---- gather 2: channel-presummed Mid[v][16]; 16 lanes/node -------------
__global__ void __launch_bounds__(256) k_g2(
    const float4* __restrict__ s1arr, const int* __restrict__ offs,
    const float4* __restrict__ Hsum, float* __restrict__ Mid, int n)
{
    int tid = blockIdx.x * blockDim.x + threadIdx.x;
    if (tid >= n * 16) return;
    int v = tid >> 4, ln = tid & 15;
    int lo = offs[v], hi = offs[v+1];
    float A0=0.f, A1=0.f;
    float px=0.f, py=0.f, pz=0.f;
    float qx=0.f, qy=0.f, qz=0.f;
    float cx=0.f, cy=0.f, cz=0.f;
    float t0=0.f, t1=0.f, t2=0.f, t3=0.f, t4=0.f;
    for (int p = lo + ln; p < hi; p += 16) {
        float4 t = s1arr[p];
        int j = __float_as_int(t.w);
        float s1x = t.x, s1y = t.y, s1z = t.z;
        float4 a = Hsum[j];
        float a0 = a.x, a1x = a.y, a1y = a.z, a1z = a.w;
        A0 += a0;
        A1 += a1x*s1x + a1y*s1y + a1z*s1z;
        px += a0*s1x; py += a0*s1y; pz += a0*s1z;
        qx += a1x;    qy += a1y;    qz += a1z;
        cx += a1y*s1z - a1z*s1y;
        cy += a1z*s1x - a1x*s1z;
        cz += a1x*s1y - a1y*s1x;
        t0 += a1x*s1y + a1y*s1x;
        t1 += a1y*s1z + a1z*s1y;
        t2 += 2.0f*a1z*s1z - a1x*s1x - a1y*s1y;
        t3 += a1x*s1z + a1z*s1x;
        t4 += a1x*s1x - a1y*s1y;
    }
    RED16(A0) RED16(A1)
    RED16(px) RED16(py) RED16(pz)
    RED16(qx) RED16(qy) RED16(qz)
    RED16(cx) RED16(cy) RED16(cz)
    RED16(t0) RED16(t1) RED16(t2) RED16(t3) RED16(t4)
    if (ln == 0) {
        const float kA = INV_SQRT2 * PW1_000;
        const float kB = INV_SQRT2 * K_V0;
        const float kP = INV_SQRT2 * K_P;
        const float kT = INV_SQRT2 * PW1_112 * NC;
        const float kU = INV_SQRT2 * PW1_112 * NC2;
        float4* md = (float4*)(Mid + v*16);
        md[0] = make_float4(kA*A0, kB*A1, kP*px, kP*py);
        md[1] = make_float4(kP*pz, kP*qx, kP*qy, kP*qz);
        md[2] = make_float4(kP*cx, kP*cy, kP*cz, kT*t0);
        md[3] = make_float4(kT*t1, kU*t2, kT*t3, kT*t4);
    }
}

// ---- gather 3: out[v]; 16 lanes/node -----------------------------------
__global__ void __launch_bounds__(256) k_g3(
    const float4* __restrict__ s1arr, const int* __restrict__ offs,
    const float* __restrict__ Mid, const float* __restrict__ Dd,
    float* __restrict__ out, int n)
{
    int tid = blockIdx.x * blockDim.x + threadIdx.x;
    if (tid >= n * 16) return;
    int v = tid >> 4, ln = tid & 15;
    int lo = offs[v], hi = offs[v+1];
    float D00 = Dd[0], D01 = Dd[1], D2a = Dd[2], D2b = Dd[3], D3 = Dd[4], D4 = Dd[5];
    float ox = 0.f, oy = 0.f, oz = 0.f;
    for (int p = lo + ln; p < hi; p += 16) {
        float4 t = s1arr[p];
        int j = __float_as_int(t.w);
        float s1x = t.x, s1y = t.y, s1z = t.z;
        const float4* m4 = (const float4*)(Mid + j*16);
        float4 ga = m4[0], gb = m4[1], gc = m4[2], gd = m4[3];
        float G0=ga.x, G1=ga.y, G2=ga.z, G3=ga.w;
        float G4=gb.x, G5=gb.y, G6=gb.z, G7=gb.w;
        float G8=gc.x, G9=gc.y, G10=gc.z, G11=gc.w;
        float G12=gd.x, G13=gd.y, G14=gd.z, G15=gd.w;
        // q1
        float q = INV_SQRT3 * (G0*D00 + G1*D01);
        ox += q * s1x; oy += q * s1y; oz += q * s1z;
        // q2
        float c1x = G3*s1z - G4*s1y;
        float c1y = G4*s1x - G2*s1z;
        float c1z = G2*s1y - G3*s1x;
        float c2x = G6*s1z - G7*s1y;
        float c2y = G7*s1x - G5*s1z;
        float c2z = G5*s1y - G6*s1x;
        ox += INV_SQRT6 * (D2a*c1x + D2b*c2x);
        oy += INV_SQRT6 * (D2a*c1y + D2b*c2y);
        oz += INV_SQRT6 * (D2a*c1z + D2b*c2z);
        // q3
        ox += INV_SQRT3 * D3 * G8;
        oy += INV_SQRT3 * D3 * G9;
        oz += INV_SQRT3 * D3 * G10;
        // q4
        ox += D4 * (NC*(s1y*G11 + s1z*G14 + s1x*G15) - NC2*s1x*G13);
        oy += D4 * (NC*(s1x*G11 + s1z*G12 - s1y*G15) - NC2*s1y*G13);
        oz += D4 * (NC*(s1y*G12 + s1x*G14) + 2.0f*NC2*s1z*G13);
    }
    RED16(ox) RED16(oy) RED16(oz)
    if (ln == 0) {
        out[v*3+0] = PW2 * INV_SQRT2 * ox;
        out[v*3+1] = PW2 * INV_SQRT2 * oy;
        out[v*3+2] = PW2 * INV_SQRT2 * oz;
    }
}

extern "C" void kernel_launch(void* const* d_in, const int* in_sizes, int n_in,
                              void* d_out, int out_size, void* d_ws, size_t ws_size,
                              hipStream_t stream) {
    const int*   nf     = (const int*)  d_in[0];
    const float* rv     = (const float*)d_in[1];
    const int*   esrc   = (const int*)  d_in[2];
    const int*   edst   = (const int*)  d_in[3];
    const float* emb    = (const float*)d_in[4];
    const float* t1_000 = (const float*)d_in[5];
    const float* t1_011 = (const float*)d_in[6];
    const float* t1_101 = (const float*)d_in[7];
    const float* t1_110 = (const float*)d_in[8];
    const float* t1_111 = (const float*)d_in[9];
    const float* t1_112 = (const float*)d_in[10];
    const float* t2_0e  = (const float*)d_in[11];
    const float* t2_1e  = (const float*)d_in[12];
    const float* t2_1o  = (const float*)d_in[13];
    const float* t2_2e  = (const float*)d_in[14];

    const int n = in_sizes[1] / 3;   // 2048 nodes
    const int E = in_sizes[2];       // 40960 edge slots (real edges + pads)

    // ws layout (all written unconditionally every call; no memset needed):
    // [Hsum n float4][s1arr E float4][Mid n*16 f][Dd 8 f][offs n+1 int]
    float4* Hsum  = (float4*)d_ws;
    float4* s1arr = Hsum + n;
    float*  Mid   = (float*)(s1arr + E);
    float*  Dd    = Mid + (size_t)n * 16;
    int*    offs  = (int*)(Dd + 8);
    float*  out   = (float*)d_out;

    const int nodeBlocks = (n * 8 + 255) / 256;
    k_prep<<<nodeBlocks + 1, 256, 0, stream>>>(
        nf, rv, esrc, edst, emb,
        t1_000, t1_011, t1_101, t1_110, t1_111, t1_112,
        t2_0e, t2_1e, t2_1o, t2_2e,
        Dd, Hsum, offs, s1arr, n, E, nodeBlocks);
    k_g2<<<(n * 16 + 255) / 256, 256, 0, stream>>>(s1arr, offs, Hsum, Mid, n);
    k_g3<<<(n * 16 + 255) / 256, 256, 0, stream>>>(s1arr, offs, Mid, Dd, out, n);
}